// Round 1
// baseline (174.504 us; speedup 1.0000x reference)
//
#include <hip/hip_runtime.h>
#include <hip/hip_bf16.h>

#define NEG 0.2f

// P layout (floats)
#define P_U   0      // 256 : u = W1 @ Wf
#define P_W   256    // 4*256 : w_t = W1 @ c_t + b1   [t*256 + hc]
#define P_PS  1280   // 4  : per-head src scale
#define P_PD  1284   // 4
#define P_QS  1288   // 16 : [t*4+h]
#define P_QD  1304   // 16
#define P_TW  1320   // 4  : softmax(temporal_attention)
#define P_CNT 1536

__device__ __forceinline__ float lrelu(float v){ return v > 0.f ? v : NEG*v; }
__device__ __forceinline__ unsigned short f2bf(float f){
    unsigned u = __float_as_uint(f);
    unsigned r = u + 0x7fffu + ((u >> 16) & 1u);
    return (unsigned short)(r >> 16);
}
__device__ __forceinline__ float bflo(unsigned u){ return __uint_as_float(u << 16); }
__device__ __forceinline__ float bfhi(unsigned u){ return __uint_as_float(u & 0xffff0000u); }

// ---------------- Phase A: tiny precompute (1 block, 256 thr) ----------------
__global__ void precomputeK(const float* time_idx, const float* Wt, const float* bt,
                            const float* Wf, const float* bf, const float* W1,
                            const float* as1, const float* ad1, const float* b1,
                            const float* ta, const float* W2,
                            float* P, uint2* W2P)
{
    int tid = threadIdx.x; // 0..255 (= hc)
    const float* wrow = W1 + tid*64;
    float uu = 0.f;
    for (int k = 0; k < 64; ++k) uu += wrow[k] * Wf[k];
    P[P_U + tid] = uu;
    for (int t = 0; t < 4; ++t){
        float ti = time_idx[t];
        float vv = 0.f;
        for (int k = 0; k < 64; ++k) vv += wrow[k] * (bf[k] + ti*Wt[k] + bt[k]);
        P[P_W + t*256 + tid] = vv + b1[tid];   // w_t (bias folded)
    }
    __syncthreads();
    if (tid < 4){ // per-head p
        int h = tid; float ps=0.f, pd=0.f;
        for (int c = 0; c < 64; ++c){
            float uv = P[P_U + h*64 + c];
            ps += uv * as1[h*64+c];
            pd += uv * ad1[h*64+c];
        }
        P[P_PS+h]=ps; P[P_PD+h]=pd;
    }
    if (tid < 16){ // q[t][h] from v = w - b1
        int t = tid >> 2, h = tid & 3;
        float qs=0.f, qd=0.f;
        for (int c = 0; c < 64; ++c){
            float v = P[P_W + t*256 + h*64 + c] - b1[h*64+c];
            qs += v * as1[h*64+c];
            qd += v * ad1[h*64+c];
        }
        P[P_QS + t*4 + h] = qs;
        P[P_QD + t*4 + h] = qd;
    }
    if (tid == 0){ // temporal softmax
        float m = ta[0];
        for (int t = 1; t < 4; ++t) m = fmaxf(m, ta[t]);
        float s = 0.f, e[4];
        for (int t = 0; t < 4; ++t){ e[t] = __expf(ta[t]-m); s += e[t]; }
        for (int t = 0; t < 4; ++t) P[P_TW+t] = e[t]/s;
    }
    // W2 packed transpose: W2P[p*64+o] = 4 bf16 of W2T[4p..4p+3][o] = W2[o][4p+k]
    for (int idx = tid; idx < 4096; idx += 256){
        int p = idx >> 6, o = idx & 63;
        unsigned b0 = f2bf(W2[o*256 + 4*p + 0]);
        unsigned b1_ = f2bf(W2[o*256 + 4*p + 1]);
        unsigned b2_ = f2bf(W2[o*256 + 4*p + 2]);
        unsigned b3 = f2bf(W2[o*256 + 4*p + 3]);
        W2P[idx] = make_uint2(b0 | (b1_<<16), b2_ | (b3<<16));
    }
}

// ---------------- CSR build ----------------
__global__ void zeroK(int* p, int n){
    int i = blockIdx.x*256 + threadIdx.x;
    if (i < n) p[i] = 0;
}
__global__ void countK(const int* ei, int E, int* deg){
    int e = blockIdx.x*256 + threadIdx.x;
    if (e < E) atomicAdd(&deg[ei[E+e]], 1);
}
__global__ void scanK(const int* deg, int* rowptr, int N){
    __shared__ int part[1024];
    int tid = threadIdx.x;
    int CH = (N + 1023) >> 10;
    int base = tid * CH;
    int sum = 0;
    for (int k = 0; k < CH; ++k){ int i = base+k; if (i < N) sum += deg[i]; }
    part[tid] = sum; __syncthreads();
    for (int off = 1; off < 1024; off <<= 1){
        int v = (tid >= off) ? part[tid-off] : 0;
        __syncthreads();
        part[tid] += v;
        __syncthreads();
    }
    int run = part[tid] - sum;  // exclusive
    for (int k = 0; k < CH; ++k){
        int i = base+k;
        if (i < N){ rowptr[i] = run; run += deg[i]; }
    }
    if (tid == 1023) rowptr[N] = part[1023];
}
__global__ void fillK(const int* ei, int E, const int* rowptr, int* cursor, int* csr){
    int e = blockIdx.x*256 + threadIdx.x;
    if (e >= E) return;
    int d = ei[E+e];
    int pos = rowptr[d] + atomicAdd(&cursor[d], 1);
    csr[pos] = ei[e];
}

// ---------------- GAT-1: online segment softmax, thread per (node, head) ----------------
__global__ void gat1K(const float* x, const int* rowptr, const int* csr,
                      const float* P, float* S, int N)
{
    int idx = blockIdx.x*256 + threadIdx.x;
    if (idx >= N*4) return;
    int n = idx >> 2, h = idx & 3;
    float ps = P[P_PS+h], pd = P[P_PD+h];
    float qs[4], qd[4];
    for (int t = 0; t < 4; ++t){ qs[t]=P[P_QS+t*4+h]; qd[t]=P[P_QD+t*4+h]; }
    float4 xv = reinterpret_cast<const float4*>(x)[n];
    float xn[4] = {xv.x, xv.y, xv.z, xv.w};
    float m[4], den[4], num[4], ad[4];
    for (int t = 0; t < 4; ++t){
        ad[t] = xn[t]*pd + qd[t];
        float e = lrelu(xn[t]*ps + qs[t] + ad[t]);   // self loop
        m[t] = e; den[t] = 1.f; num[t] = xn[t];
    }
    int beg = rowptr[n], end = rowptr[n+1];
    for (int j = beg; j < end; ++j){
        int s = csr[j];
        float4 sv = reinterpret_cast<const float4*>(x)[s];
        float xs[4] = {sv.x, sv.y, sv.z, sv.w};
        for (int t = 0; t < 4; ++t){
            float e = lrelu(xs[t]*ps + qs[t] + ad[t]);
            if (e > m[t]){
                float f = __expf(m[t]-e);
                den[t] *= f; num[t] *= f; m[t] = e;
            }
            float ex = __expf(e - m[t]);
            den[t] += ex; num[t] += ex*xs[t];
        }
    }
    for (int t = 0; t < 4; ++t) S[(n*4+h)*4 + t] = num[t]/den[t];
}

// ---------------- h2 = combined @ W2^T (+ attention logit dots) ----------------
__launch_bounds__(256)
__global__ void h2K(const float* S, const float* P, const uint2* W2Pg,
                    const float* as2, const float* ad2,
                    float* h2, float* als2, float* ald2, int N)
{
    __shared__ uint2 W2Plds[4096];     // 32 KB
    __shared__ float comb[4][256];     // 4 KB
    __shared__ float Pl[1344];         // u, w, tw
    int tid = threadIdx.x;
    for (int i = tid; i < 4096; i += 256) W2Plds[i] = W2Pg[i];
    for (int i = tid; i < 1344; i += 256) Pl[i] = P[i];
    __syncthreads();
    int wv = tid >> 6, lane = tid & 63;
    float a_s = as2[lane], a_d = ad2[lane];
    for (int k = 0; k < 4; ++k){
        int n = blockIdx.x*16 + wv*4 + k;
        __syncthreads();
        if (n < N){
            for (int h = 0; h < 4; ++h){
                float uu = Pl[P_U + h*64 + lane];
                float val = 0.f;
                for (int t = 0; t < 4; ++t){
                    float s  = S[(n*4+h)*4 + t];
                    float wt = Pl[P_W + t*256 + h*64 + lane];
                    float r  = s*uu + wt;
                    r = r > 0.f ? r : 0.f;
                    val += Pl[P_TW+t]*r;
                }
                comb[wv][h*64 + lane] = val;
            }
        }
        __syncthreads();
        if (n < N){
            const float4* cv = reinterpret_cast<const float4*>(comb[wv]);
            float acc = 0.f;
            #pragma unroll 8
            for (int p = 0; p < 64; ++p){
                uint2 wp = W2Plds[p*64 + lane];
                float4 cb = cv[p];
                acc += cb.x * bflo(wp.x);
                acc += cb.y * bfhi(wp.x);
                acc += cb.z * bflo(wp.y);
                acc += cb.w * bfhi(wp.y);
            }
            h2[n*64 + lane] = acc;
            float s1 = acc * a_s, s2 = acc * a_d;
            #pragma unroll
            for (int off = 32; off > 0; off >>= 1){
                s1 += __shfl_xor(s1, off);
                s2 += __shfl_xor(s2, off);
            }
            if (lane == 0){ als2[n] = s1; ald2[n] = s2; }
        }
    }
}

// ---------------- GAT-2: wave per node, online softmax + gathered PV ----------------
__global__ void gat2K(const float* h2, const float* als2, const float* ald2,
                      const int* rowptr, const int* csr, const float* b2,
                      float* out, int N)
{
    int gw = (blockIdx.x*256 + threadIdx.x) >> 6;
    if (gw >= N) return;
    int n = gw, lane = threadIdx.x & 63;
    float aldn = ald2[n];
    float m = lrelu(als2[n] + aldn);   // self loop
    float den = 1.f;
    float acc = h2[n*64 + lane];
    int beg = rowptr[n], end = rowptr[n+1];
    for (int base = beg; base < end; base += 64){
        int j = base + lane;
        bool valid = j < end;
        int s = valid ? csr[j] : 0;
        float e = valid ? lrelu(als2[s] + aldn) : -INFINITY;
        float cm = e;
        #pragma unroll
        for (int off = 32; off > 0; off >>= 1) cm = fmaxf(cm, __shfl_xor(cm, off));
        float nm = fmaxf(m, cm);
        float f = __expf(m - nm);
        den *= f; acc *= f;
        float ex = valid ? __expf(e - nm) : 0.f;
        float sx = ex;
        #pragma unroll
        for (int off = 32; off > 0; off >>= 1) sx += __shfl_xor(sx, off);
        den += sx;
        int cnt = min(64, end - base);
        for (int i = 0; i < cnt; ++i){
            float eb = __shfl(ex, i);
            int   sb = __shfl(s, i);
            acc += eb * h2[sb*64 + lane];
        }
        m = nm;
    }
    out[n*64 + lane] = acc/den + b2[lane];
}

extern "C" void kernel_launch(void* const* d_in, const int* in_sizes, int n_in,
                              void* d_out, int out_size, void* d_ws, size_t ws_size,
                              hipStream_t stream)
{
    const float* x        = (const float*)d_in[0];
    const int*   ei       = (const int*)  d_in[1];
    const float* time_idx = (const float*)d_in[2];
    const float* Wt       = (const float*)d_in[3];
    const float* bt       = (const float*)d_in[4];
    const float* Wf       = (const float*)d_in[5];
    const float* bf       = (const float*)d_in[6];
    const float* W1       = (const float*)d_in[7];
    const float* as1      = (const float*)d_in[8];
    const float* ad1      = (const float*)d_in[9];
    const float* b1       = (const float*)d_in[10];
    const float* ta       = (const float*)d_in[11];
    const float* W2       = (const float*)d_in[12];
    const float* as2      = (const float*)d_in[13];
    const float* ad2      = (const float*)d_in[14];
    const float* b2       = (const float*)d_in[15];

    int N = in_sizes[0] / 4;   // x: [1,N,4]
    int E = in_sizes[1] / 2;   // edge_index: [2,E]

    char* w = (char*)d_ws;
    auto al = [](size_t v){ return (v + 255) & ~(size_t)255; };
    size_t off = 0;
    float* P     = (float*)(w + off); off = al(off + P_CNT*sizeof(float));
    uint2* W2P   = (uint2*)(w + off); off = al(off + 4096*sizeof(uint2));
    int*   deg   = (int*)  (w + off); off = al(off + (size_t)N*2*sizeof(int));
    int*   cursor = deg + N;
    int*   rowptr= (int*)  (w + off); off = al(off + ((size_t)N+1)*sizeof(int));
    int*   csr   = (int*)  (w + off); off = al(off + (size_t)E*sizeof(int));
    float* S     = (float*)(w + off); off = al(off + (size_t)N*16*sizeof(float));
    float* h2    = (float*)(w + off); off = al(off + (size_t)N*64*sizeof(float));
    float* als2  = (float*)(w + off); off = al(off + (size_t)N*sizeof(float));
    float* ald2  = (float*)(w + off); off = al(off + (size_t)N*sizeof(float));
    (void)off; (void)ws_size; (void)n_in; (void)out_size;

    precomputeK<<<1, 256, 0, stream>>>(time_idx, Wt, bt, Wf, bf, W1, as1, ad1, b1, ta, W2, P, W2P);
    zeroK<<<(2*N + 255)/256, 256, 0, stream>>>(deg, 2*N);
    countK<<<(E + 255)/256, 256, 0, stream>>>(ei, E, deg);
    scanK<<<1, 1024, 0, stream>>>(deg, rowptr, N);
    fillK<<<(E + 255)/256, 256, 0, stream>>>(ei, E, rowptr, cursor, csr);
    gat1K<<<(4*N + 255)/256, 256, 0, stream>>>(x, rowptr, csr, P, S, N);
    h2K<<<(N + 15)/16, 256, 0, stream>>>(S, P, W2P, as2, ad2, h2, als2, ald2, N);
    gat2K<<<((size_t)N*64 + 255)/256, 256, 0, stream>>>(h2, als2, ald2, rowptr, csr, b2, (float*)d_out, N);
}

// Round 2
// 159.150 us; speedup vs baseline: 1.0965x; 1.0965x over previous
//
#include <hip/hip_runtime.h>
#include <hip/hip_bf16.h>

#define NEG 0.2f

// P layout (floats)
#define P_U   0      // 256 : u = W1 @ Wf
#define P_W   256    // 4*256 : w_t = W1 @ c_t + b1   [t*256 + hc]
#define P_PS  1280   // 4  : per-head src scale
#define P_PD  1284   // 4
#define P_QS  1288   // 16 : [t*4+h]
#define P_QD  1304   // 16
#define P_TW  1320   // 4  : softmax(temporal_attention)
#define P_WT  1324   // 1024 : wT[c*4+t] = P_W[t*256+c]  (float4-aligned: 1324%4==0)
#define P_CNT 2560

typedef __bf16 bf16x8 __attribute__((ext_vector_type(8)));
typedef float  f32x4  __attribute__((ext_vector_type(4)));

__device__ __forceinline__ float lrelu(float v){ return v > 0.f ? v : NEG*v; }
__device__ __forceinline__ unsigned short f2bf(float f){
    unsigned u = __float_as_uint(f);
    unsigned r = u + 0x7fffu + ((u >> 16) & 1u);
    return (unsigned short)(r >> 16);
}

// ---------------- Phase A: tiny precompute (1 block, 256 thr) ----------------
__global__ void precomputeK(const float* time_idx, const float* Wt, const float* bt,
                            const float* Wf, const float* bf, const float* W1,
                            const float* as1, const float* ad1, const float* b1,
                            const float* ta, const float* W2,
                            float* P, unsigned short* W2bf)
{
    int tid = threadIdx.x; // 0..255 (= hc)
    const float* wrow = W1 + tid*64;
    float uu = 0.f;
    for (int k = 0; k < 64; ++k) uu += wrow[k] * Wf[k];
    P[P_U + tid] = uu;
    for (int t = 0; t < 4; ++t){
        float ti = time_idx[t];
        float vv = 0.f;
        for (int k = 0; k < 64; ++k) vv += wrow[k] * (bf[k] + ti*Wt[k] + bt[k]);
        P[P_W + t*256 + tid] = vv + b1[tid];   // w_t (bias folded)
    }
    __syncthreads();
    if (tid < 4){ // per-head p
        int h = tid; float ps=0.f, pd=0.f;
        for (int c = 0; c < 64; ++c){
            float uv = P[P_U + h*64 + c];
            ps += uv * as1[h*64+c];
            pd += uv * ad1[h*64+c];
        }
        P[P_PS+h]=ps; P[P_PD+h]=pd;
    }
    if (tid < 16){ // q[t][h] from v = w - b1
        int t = tid >> 2, h = tid & 3;
        float qs=0.f, qd=0.f;
        for (int c = 0; c < 64; ++c){
            float v = P[P_W + t*256 + h*64 + c] - b1[h*64+c];
            qs += v * as1[h*64+c];
            qd += v * ad1[h*64+c];
        }
        P[P_QS + t*4 + h] = qs;
        P[P_QD + t*4 + h] = qd;
    }
    if (tid == 0){ // temporal softmax
        float m = ta[0];
        for (int t = 1; t < 4; ++t) m = fmaxf(m, ta[t]);
        float s = 0.f, e[4];
        for (int t = 0; t < 4; ++t){ e[t] = __expf(ta[t]-m); s += e[t]; }
        for (int t = 0; t < 4; ++t) P[P_TW+t] = e[t]/s;
    }
    // transposed w table for h2K phase-1 (needs P_W complete -> after barrier)
    for (int idx = tid; idx < 1024; idx += 256){
        int c = idx >> 2, t = idx & 3;
        P[P_WT + idx] = P[P_W + t*256 + c];
    }
    // W2 in bf16, plain row-major [out][k]
    for (int idx = tid; idx < 16384; idx += 256)
        W2bf[idx] = f2bf(W2[idx]);
}

// ---------------- CSR build ----------------
__global__ void zeroK(int* p, int n){
    int i = blockIdx.x*256 + threadIdx.x;
    if (i < n) p[i] = 0;
}
__global__ void countK(const int* ei, int E, int* deg){
    int e = blockIdx.x*256 + threadIdx.x;
    if (e < E) atomicAdd(&deg[ei[E+e]], 1);
}
__global__ void scanK(const int* deg, int* rowptr, int N){
    __shared__ int part[1024];
    int tid = threadIdx.x;
    int CH = (N + 1023) >> 10;
    int base = tid * CH;
    int sum = 0;
    for (int k = 0; k < CH; ++k){ int i = base+k; if (i < N) sum += deg[i]; }
    part[tid] = sum; __syncthreads();
    for (int off = 1; off < 1024; off <<= 1){
        int v = (tid >= off) ? part[tid-off] : 0;
        __syncthreads();
        part[tid] += v;
        __syncthreads();
    }
    int run = part[tid] - sum;  // exclusive
    for (int k = 0; k < CH; ++k){
        int i = base+k;
        if (i < N){ rowptr[i] = run; run += deg[i]; }
    }
    if (tid == 1023) rowptr[N] = part[1023];
}
__global__ void fillK(const int* ei, int E, const int* rowptr, int* cursor, int* csr){
    int e = blockIdx.x*256 + threadIdx.x;
    if (e >= E) return;
    int d = ei[E+e];
    int pos = rowptr[d] + atomicAdd(&cursor[d], 1);
    csr[pos] = ei[e];
}

// ---------------- GAT-1: online segment softmax, thread per (node, head) ----------------
__global__ void gat1K(const float* x, const int* rowptr, const int* csr,
                      const float* P, float* S, int N)
{
    int idx = blockIdx.x*256 + threadIdx.x;
    if (idx >= N*4) return;
    int n = idx >> 2, h = idx & 3;
    float ps = P[P_PS+h], pd = P[P_PD+h];
    float qs[4], qd[4];
    for (int t = 0; t < 4; ++t){ qs[t]=P[P_QS+t*4+h]; qd[t]=P[P_QD+t*4+h]; }
    float4 xv = reinterpret_cast<const float4*>(x)[n];
    float xn[4] = {xv.x, xv.y, xv.z, xv.w};
    float m[4], den[4], num[4], ad[4];
    for (int t = 0; t < 4; ++t){
        ad[t] = xn[t]*pd + qd[t];
        float e = lrelu(xn[t]*ps + qs[t] + ad[t]);   // self loop
        m[t] = e; den[t] = 1.f; num[t] = xn[t];
    }
    int beg = rowptr[n], end = rowptr[n+1];
    for (int j = beg; j < end; ++j){
        int s = csr[j];
        float4 sv = reinterpret_cast<const float4*>(x)[s];
        float xs[4] = {sv.x, sv.y, sv.z, sv.w};
        for (int t = 0; t < 4; ++t){
            float e = lrelu(xs[t]*ps + qs[t] + ad[t]);
            if (e > m[t]){
                float f = __expf(m[t]-e);
                den[t] *= f; num[t] *= f; m[t] = e;
            }
            float ex = __expf(e - m[t]);
            den[t] += ex; num[t] += ex*xs[t];
        }
    }
    for (int t = 0; t < 4; ++t) S[(n*4+h)*4 + t] = num[t]/den[t];
}

// ---------------- h2 = combined @ W2^T via MFMA (+ attention logit dots) ----------------
// block: 256 thr (4 waves), 64 nodes. Wave w: nodes [w*16, w*16+16), full 64 outs.
__launch_bounds__(256)
__global__ void h2K(const float* S, const float* P, const unsigned short* W2bfg,
                    const float* as2, const float* ad2,
                    float* h2, float* als2, float* ald2, int N)
{
    __shared__ unsigned short Abf[64*264];   // bf16 combined, row pad 264 (2-way banks)
    __shared__ float  Ul[256];
    __shared__ float4 WTl[256];
    __shared__ float  Twl[4];
    int tid = threadIdx.x;
    Ul[tid] = P[P_U + tid];
    WTl[tid] = reinterpret_cast<const float4*>(P + P_WT)[tid];
    if (tid < 4) Twl[tid] = P[P_TW + tid];
    __syncthreads();

    // phase 1: combined -> bf16 A tile
    int nl = tid >> 2, q = tid & 3;
    int gn = blockIdx.x*64 + nl;
    float tw0 = Twl[0], tw1 = Twl[1], tw2 = Twl[2], tw3 = Twl[3];
    unsigned int* arow = reinterpret_cast<unsigned int*>(&Abf[nl*264 + q*64]);
    if (gn < N){
        float4 s4 = reinterpret_cast<const float4*>(S)[gn*4 + q];
        #pragma unroll 8
        for (int j = 0; j < 64; j += 2){
            int c = q*64 + j;
            float4 wa = WTl[c];
            float4 wb = WTl[c+1];
            float ua = Ul[c], ub = Ul[c+1];
            float v0 = tw0*fmaxf(s4.x*ua + wa.x, 0.f)
                     + tw1*fmaxf(s4.y*ua + wa.y, 0.f)
                     + tw2*fmaxf(s4.z*ua + wa.z, 0.f)
                     + tw3*fmaxf(s4.w*ua + wa.w, 0.f);
            float v1 = tw0*fmaxf(s4.x*ub + wb.x, 0.f)
                     + tw1*fmaxf(s4.y*ub + wb.y, 0.f)
                     + tw2*fmaxf(s4.z*ub + wb.z, 0.f)
                     + tw3*fmaxf(s4.w*ub + wb.w, 0.f);
            arow[j>>1] = (unsigned)f2bf(v0) | ((unsigned)f2bf(v1) << 16);
        }
    } else {
        #pragma unroll
        for (int j = 0; j < 32; ++j) arow[j] = 0;
    }
    __syncthreads();

    // phase 2: MFMA 16x16x32, A from LDS, B (W2 bf16) from global (L1/L2-resident)
    int w = tid >> 6, lane = tid & 63, lr = lane & 15, lhi = lane >> 4;
    int r0 = w*16;
    bf16x8 a[8];
    #pragma unroll
    for (int kk = 0; kk < 8; ++kk)
        a[kk] = *reinterpret_cast<const bf16x8*>(&Abf[(r0+lr)*264 + kk*32 + lhi*8]);
    float s1[4] = {0.f,0.f,0.f,0.f}, s2[4] = {0.f,0.f,0.f,0.f};
    int gbase = blockIdx.x*64 + r0 + lhi*4;
    #pragma unroll
    for (int nt = 0; nt < 4; ++nt){
        f32x4 acc = {0.f,0.f,0.f,0.f};
        const unsigned short* bp = W2bfg + (nt*16 + lr)*256 + lhi*8;
        #pragma unroll
        for (int kk = 0; kk < 8; ++kk){
            bf16x8 b = *reinterpret_cast<const bf16x8*>(bp + kk*32);
            acc = __builtin_amdgcn_mfma_f32_16x16x32_bf16(a[kk], b, acc, 0, 0, 0);
        }
        float oas = as2[nt*16 + lr], oad = ad2[nt*16 + lr];
        #pragma unroll
        for (int r = 0; r < 4; ++r){
            int g = gbase + r;
            if (g < N) h2[g*64 + nt*16 + lr] = acc[r];
            s1[r] += acc[r]*oas;
            s2[r] += acc[r]*oad;
        }
    }
    #pragma unroll
    for (int r = 0; r < 4; ++r){
        float v1 = s1[r], v2 = s2[r];
        #pragma unroll
        for (int off = 8; off > 0; off >>= 1){
            v1 += __shfl_xor(v1, off);
            v2 += __shfl_xor(v2, off);
        }
        int g = gbase + r;
        if (lr == 0 && g < N){ als2[g] = v1; ald2[g] = v2; }
    }
}

// ---------------- GAT-2: wave per node, online softmax + gathered PV ----------------
__global__ void gat2K(const float* h2, const float* als2, const float* ald2,
                      const int* rowptr, const int* csr, const float* b2,
                      float* out, int N)
{
    int gw = (blockIdx.x*256 + threadIdx.x) >> 6;
    if (gw >= N) return;
    int n = gw, lane = threadIdx.x & 63;
    float aldn = ald2[n];
    float m = lrelu(als2[n] + aldn);   // self loop
    float den = 1.f;
    float acc = h2[n*64 + lane];
    int beg = rowptr[n], end = rowptr[n+1];
    for (int base = beg; base < end; base += 64){
        int j = base + lane;
        bool valid = j < end;
        int s = valid ? csr[j] : 0;
        float e = valid ? lrelu(als2[s] + aldn) : -INFINITY;
        float cm = e;
        #pragma unroll
        for (int off = 32; off > 0; off >>= 1) cm = fmaxf(cm, __shfl_xor(cm, off));
        float nm = fmaxf(m, cm);
        float f = __expf(m - nm);
        den *= f; acc *= f;
        float ex = valid ? __expf(e - nm) : 0.f;
        float sx = ex;
        #pragma unroll
        for (int off = 32; off > 0; off >>= 1) sx += __shfl_xor(sx, off);
        den += sx;
        int cnt = min(64, end - base);
        for (int i = 0; i < cnt; ++i){
            float eb = __shfl(ex, i);
            int   sb = __shfl(s, i);
            acc += eb * h2[sb*64 + lane];
        }
        m = nm;
    }
    out[n*64 + lane] = acc/den + b2[lane];
}

extern "C" void kernel_launch(void* const* d_in, const int* in_sizes, int n_in,
                              void* d_out, int out_size, void* d_ws, size_t ws_size,
                              hipStream_t stream)
{
    const float* x        = (const float*)d_in[0];
    const int*   ei       = (const int*)  d_in[1];
    const float* time_idx = (const float*)d_in[2];
    const float* Wt       = (const float*)d_in[3];
    const float* bt       = (const float*)d_in[4];
    const float* Wf       = (const float*)d_in[5];
    const float* bf       = (const float*)d_in[6];
    const float* W1       = (const float*)d_in[7];
    const float* as1      = (const float*)d_in[8];
    const float* ad1      = (const float*)d_in[9];
    const float* b1       = (const float*)d_in[10];
    const float* ta       = (const float*)d_in[11];
    const float* W2       = (const float*)d_in[12];
    const float* as2      = (const float*)d_in[13];
    const float* ad2      = (const float*)d_in[14];
    const float* b2       = (const float*)d_in[15];

    int N = in_sizes[0] / 4;   // x: [1,N,4]
    int E = in_sizes[1] / 2;   // edge_index: [2,E]

    char* w = (char*)d_ws;
    auto al = [](size_t v){ return (v + 255) & ~(size_t)255; };
    size_t off = 0;
    float* P     = (float*)(w + off); off = al(off + P_CNT*sizeof(float));
    unsigned short* W2bf = (unsigned short*)(w + off); off = al(off + 16384*sizeof(unsigned short));
    int*   deg   = (int*)  (w + off); off = al(off + (size_t)N*2*sizeof(int));
    int*   cursor = deg + N;
    int*   rowptr= (int*)  (w + off); off = al(off + ((size_t)N+1)*sizeof(int));
    int*   csr   = (int*)  (w + off); off = al(off + (size_t)E*sizeof(int));
    float* S     = (float*)(w + off); off = al(off + (size_t)N*16*sizeof(float));
    float* h2    = (float*)(w + off); off = al(off + (size_t)N*64*sizeof(float));
    float* als2  = (float*)(w + off); off = al(off + (size_t)N*sizeof(float));
    float* ald2  = (float*)(w + off); off = al(off + (size_t)N*sizeof(float));
    (void)off; (void)ws_size; (void)n_in; (void)out_size;

    precomputeK<<<1, 256, 0, stream>>>(time_idx, Wt, bt, Wf, bf, W1, as1, ad1, b1, ta, W2, P, W2bf);
    zeroK<<<(2*N + 255)/256, 256, 0, stream>>>(deg, 2*N);
    countK<<<(E + 255)/256, 256, 0, stream>>>(ei, E, deg);
    scanK<<<1, 1024, 0, stream>>>(deg, rowptr, N);
    fillK<<<(E + 255)/256, 256, 0, stream>>>(ei, E, rowptr, cursor, csr);
    gat1K<<<(4*N + 255)/256, 256, 0, stream>>>(x, rowptr, csr, P, S, N);
    h2K<<<(N + 63)/64, 256, 0, stream>>>(S, P, W2bf, as2, ad2, h2, als2, ald2, N);
    gat2K<<<((size_t)N*64 + 255)/256, 256, 0, stream>>>(h2, als2, ald2, rowptr, csr, b2, (float*)d_out, N);
}